// Round 18
// baseline (100.833 us; speedup 1.0000x reference)
//
#include <hip/hip_runtime.h>

#define BB 8
#define NN 256
#define DD 128
#define LN_EPS 1e-5f

// Inter-block sync state: zero-initialized at module load; each call resets
// to zero at the end -> deterministic across graph replays, and the harness
// workspace poison never touches device globals.
__device__ int g_cnt[BB];
__device__ int g_done[BB];

// ---------------------------------------------------------------------------
// kf_all: single kernel. 256 blocks (8 rows each) x 512 threads, XCD-affine
// (b = bid & 7). Phase 1 = proj (champion body): hi stays in LDS, hjb ->
// global. Batch-scoped spin sync (adjacency staged during the wait window).
// Phase 2 = champion pair + tail + LN.
// __launch_bounds__(512, 2): VGPR cap 128. Plain (512) let the compiler pick
// a 64-VGPR budget -> stage B spilled to scratch -> 103 us (R17 post-mortem).
// smem floats:
//  [0,8192)     phase1 part_a@0/part_b@4096 ; phase2 hjs tile / partT
//  [8192,10240) a_t[8][256] ; aliases u1s@8192, resS@9216 after pair
//  [10240,11264) xs[8][128]
//  [11264,13312) ssp[16][128] (aggs = upper half @12288)
//  [13312,13320) asum_s[8]
//  [13320,14344) his[8][128]
// ---------------------------------------------------------------------------
__global__ __launch_bounds__(512, 2) void kf_all(const float* __restrict__ adj,
                                                 const float* __restrict__ x,
                                                 const float* __restrict__ w1,
                                                 const float* __restrict__ b1,
                                                 const float* __restrict__ w2,
                                                 const float* __restrict__ b2,
                                                 const float* __restrict__ w3,
                                                 const float* __restrict__ b3,
                                                 const float* __restrict__ w4,
                                                 const float* __restrict__ b4,
                                                 const float* __restrict__ g,
                                                 const float* __restrict__ bet,
                                                 float* __restrict__ hjb,
                                                 float* __restrict__ out) {
    __shared__ float smem[14344];
    float* const part   = smem;           // phase1 parts / phase2 hjs+partT
    float* const a_t    = smem + 8192;    // [8][256]
    float* const u1s    = smem + 8192;    // alias (a_t dead after pair)
    float* const resS   = smem + 9216;    // alias
    float* const xs     = smem + 10240;   // [8][128]
    float* const ssp    = smem + 11264;   // [16][128]
    float* const aggs   = smem + 12288;   // upper half of ssp
    float* const asum_s = smem + 13312;   // [8]
    float* const his    = smem + 13320;   // [8][128]

    const int bid   = blockIdx.x;
    const int b     = bid & 7;            // XCD-affine batch
    const int i0    = (bid >> 3) * 8;
    const int row0g = b * NN + i0;
    const int tid   = threadIdx.x;

    // ================= phase 1: proj =================
    #pragma unroll
    for (int t = 0; t < 2; ++t) {
        int idx = tid + t * 512;
        xs[idx] = x[row0g * DD + idx];
    }
    __syncthreads();

    {
        const int dp = tid & 127;
        const int kg = tid >> 7;     // 0..3
        const int kb = kg * 32;
        float acc_a[8] = {}, acc_b[8] = {};
        #pragma unroll
        for (int k4 = 0; k4 < 8; ++k4) {
            const int k0 = kb + k4 * 4;
            float wa[4], wb[4];
            #pragma unroll
            for (int q = 0; q < 4; ++q) {
                wa[q] = w1[(k0 + q) * DD + dp];
                wb[q] = w1[(DD + k0 + q) * DD + dp];
            }
            #pragma unroll
            for (int r = 0; r < 8; ++r) {
                const float4 xv = *(const float4*)&xs[r * DD + k0];  // broadcast
                acc_a[r] = fmaf(xv.x, wa[0], acc_a[r]);
                acc_a[r] = fmaf(xv.y, wa[1], acc_a[r]);
                acc_a[r] = fmaf(xv.z, wa[2], acc_a[r]);
                acc_a[r] = fmaf(xv.w, wa[3], acc_a[r]);
                acc_b[r] = fmaf(xv.x, wb[0], acc_b[r]);
                acc_b[r] = fmaf(xv.y, wb[1], acc_b[r]);
                acc_b[r] = fmaf(xv.z, wb[2], acc_b[r]);
                acc_b[r] = fmaf(xv.w, wb[3], acc_b[r]);
            }
        }
        #pragma unroll
        for (int r = 0; r < 8; ++r) {
            part[kg * 1024 + r * DD + dp]        = acc_a[r];
            part[4096 + kg * 1024 + r * DD + dp] = acc_b[r];
        }
    }
    __syncthreads();
    #pragma unroll
    for (int m = 0; m < 2; ++m) {
        int idx = tid + m * 512;            // 0..1023
        int r = idx >> 7, d = idx & 127;
        float sa = 0.f, sb = 0.f;
        #pragma unroll
        for (int w = 0; w < 4; ++w) {
            sa += part[w * 1024 + r * DD + d];
            sb += part[4096 + w * 1024 + r * DD + d];
        }
        his[r * DD + d] = sa;                                  // hi -> LDS only
        hjb[(size_t)(row0g + r) * DD + d] = sb + b1[d];        // hjb -> global
    }
    // release: each thread fences its hjb stores, then one signal per block
    __threadfence();
    __syncthreads();
    if (tid == 0)
        __hip_atomic_fetch_add(&g_cnt[b], 1, __ATOMIC_RELEASE,
                               __HIP_MEMORY_SCOPE_AGENT);

    // ---- stage masked adjacency during the wait window (independent work)
    #pragma unroll
    for (int t = 0; t < 4; ++t) {
        int idx = tid + t * 512;            // 0..2047
        int il = idx >> 8, j = idx & 255;
        int ig = i0 + il;
        float av = adj[((size_t)b * NN + ig) * NN + j];
        a_t[il * 256 + j] = (j == ig) ? 0.f : av;
    }

    // ---- spin until all 32 blocks of this batch published hjb
    if (tid == 0) {
        while (__hip_atomic_load(&g_cnt[b], __ATOMIC_ACQUIRE,
                                 __HIP_MEMORY_SCOPE_AGENT) < 32)
            __builtin_amdgcn_s_sleep(2);
        int od = __hip_atomic_fetch_add(&g_done[b], 1, __ATOMIC_RELAXED,
                                        __HIP_MEMORY_SCOPE_AGENT);
        if (od == 31) {   // last block of batch past the gate: reset for next call
            __hip_atomic_store(&g_cnt[b], 0, __ATOMIC_RELAXED,
                               __HIP_MEMORY_SCOPE_AGENT);
            __hip_atomic_store(&g_done[b], 0, __ATOMIC_RELAXED,
                               __HIP_MEMORY_SCOPE_AGENT);
        }
    }
    __syncthreads();
    __threadfence();   // acquire side: invalidate caches before reading hjb

    // ---- asum: one wave per row from a_t
    {
        int w = tid >> 6, l = tid & 63;
        float s = a_t[w * 256 + l] + a_t[w * 256 + l + 64]
                + a_t[w * 256 + l + 128] + a_t[w * 256 + l + 192];
        #pragma unroll
        for (int m = 32; m; m >>= 1) s += __shfl_xor(s, m);
        if (l == 0) asum_s[w] = s;
    }

    // ================= phase 2: pair (champion) =================
    const int dq  = tid & 31;       // d-quad
    const int rg  = tid >> 5;       // 0..15
    const int row = rg & 7;
    const int jh  = rg >> 3;
    const float4 hi4 = *(const float4*)&his[row * DD + dq * 4];
    float4 acc = {0.f, 0.f, 0.f, 0.f};

    for (int jt = 0; jt < 4; ++jt) {
        __syncthreads();   // prev tile reads done (also covers asum_s/a_t)
        const float4* src = (const float4*)(hjb + ((size_t)b * NN + jt * 64) * DD);
        float4* dst = (float4*)smem;
        #pragma unroll
        for (int t = 0; t < 4; ++t) dst[tid + t * 512] = src[tid + t * 512];
        __syncthreads();
        const int jb = jh * 32;
        #pragma unroll 8
        for (int jj = 0; jj < 32; ++jj) {
            const int jl = jb + jj;
            const float4 hv = *(const float4*)&smem[jl * 128 + dq * 4];
            const float a = a_t[row * 256 + jt * 64 + jl];
            acc.x = fmaf(fmaxf(hi4.x + hv.x, 0.f), a, acc.x);
            acc.y = fmaf(fmaxf(hi4.y + hv.y, 0.f), a, acc.y);
            acc.z = fmaf(fmaxf(hi4.z + hv.z, 0.f), a, acc.z);
            acc.w = fmaf(fmaxf(hi4.w + hv.w, 0.f), a, acc.w);
        }
    }
    __syncthreads();       // last hjs reads done
    *(float4*)&ssp[rg * 128 + dq * 4] = acc;
    __syncthreads();
    // combine j-halves into lower half
    #pragma unroll
    for (int t = 0; t < 2; ++t) {
        int idx = tid + t * 512;
        int r = idx >> 7, d = idx & 127;
        ssp[r * 128 + d] += ssp[(r + 8) * 128 + d];
    }
    __syncthreads();

    // ================= tail (champion) =================
    const int dp = tid & 63;            // cols dp, dp+64
    const int kg = tid >> 6;            // 0..7 (wave-uniform)
    const int kb = kg * 16;

    // stage A: agg = ss @ w2 (+ b2*asum at combine)
    {
        float wv0[16], wv1[16];
        #pragma unroll
        for (int k = 0; k < 16; ++k) {
            wv0[k] = w2[(kb + k) * DD + dp];
            wv1[k] = w2[(kb + k) * DD + dp + 64];
        }
        #pragma unroll
        for (int r = 0; r < 8; ++r) {
            float a0 = 0.f, a1 = 0.f;
            #pragma unroll
            for (int q = 0; q < 4; ++q) {
                const float4 sv = *(const float4*)&ssp[r * 128 + kb + q * 4];
                a0 = fmaf(sv.x, wv0[q*4+0], a0); a1 = fmaf(sv.x, wv1[q*4+0], a1);
                a0 = fmaf(sv.y, wv0[q*4+1], a0); a1 = fmaf(sv.y, wv1[q*4+1], a1);
                a0 = fmaf(sv.z, wv0[q*4+2], a0); a1 = fmaf(sv.z, wv1[q*4+2], a1);
                a0 = fmaf(sv.w, wv0[q*4+3], a0); a1 = fmaf(sv.w, wv1[q*4+3], a1);
            }
            part[kg * 1024 + r * 128 + dp]      = a0;
            part[kg * 1024 + r * 128 + dp + 64] = a1;
        }
    }
    __syncthreads();
    #pragma unroll
    for (int m = 0; m < 2; ++m) {
        int idx = tid + m * 512;
        int r = idx >> 7, d = idx & 127;
        float s = part[idx];
        #pragma unroll
        for (int w = 1; w < 8; ++w) s += part[w * 1024 + idx];
        aggs[idx] = s + b2[d] * asum_s[r];
    }
    __syncthreads();

    // stage B: u1 = relu(x@w3a + agg@w3b + b3)
    {
        float wa0[16], wa1[16], wb0[16], wb1[16];
        #pragma unroll
        for (int k = 0; k < 16; ++k) {
            wa0[k] = w3[(kb + k) * DD + dp];
            wa1[k] = w3[(kb + k) * DD + dp + 64];
            wb0[k] = w3[(DD + kb + k) * DD + dp];
            wb1[k] = w3[(DD + kb + k) * DD + dp + 64];
        }
        #pragma unroll
        for (int r = 0; r < 8; ++r) {
            float a0 = 0.f, a1 = 0.f;
            #pragma unroll
            for (int q = 0; q < 4; ++q) {
                const float4 xv = *(const float4*)&xs[r * 128 + kb + q * 4];
                const float4 av = *(const float4*)&aggs[r * 128 + kb + q * 4];
                a0 = fmaf(xv.x, wa0[q*4+0], a0); a1 = fmaf(xv.x, wa1[q*4+0], a1);
                a0 = fmaf(xv.y, wa0[q*4+1], a0); a1 = fmaf(xv.y, wa1[q*4+1], a1);
                a0 = fmaf(xv.z, wa0[q*4+2], a0); a1 = fmaf(xv.z, wa1[q*4+2], a1);
                a0 = fmaf(xv.w, wa0[q*4+3], a0); a1 = fmaf(xv.w, wa1[q*4+3], a1);
                a0 = fmaf(av.x, wb0[q*4+0], a0); a1 = fmaf(av.x, wb1[q*4+0], a1);
                a0 = fmaf(av.y, wb0[q*4+1], a0); a1 = fmaf(av.y, wb1[q*4+1], a1);
                a0 = fmaf(av.z, wb0[q*4+2], a0); a1 = fmaf(av.z, wb1[q*4+2], a1);
                a0 = fmaf(av.w, wb0[q*4+3], a0); a1 = fmaf(av.w, wb1[q*4+3], a1);
            }
            part[kg * 1024 + r * 128 + dp]      = a0;
            part[kg * 1024 + r * 128 + dp + 64] = a1;
        }
    }
    __syncthreads();
    #pragma unroll
    for (int m = 0; m < 2; ++m) {
        int idx = tid + m * 512;
        int r = idx >> 7, d = idx & 127;
        float s = part[idx];
        #pragma unroll
        for (int w = 1; w < 8; ++w) s += part[w * 1024 + idx];
        u1s[idx] = fmaxf(s + b3[d], 0.f);
    }
    __syncthreads();

    // stage C: upd = u1 @ w4; res = x + upd + b4
    {
        float wv0[16], wv1[16];
        #pragma unroll
        for (int k = 0; k < 16; ++k) {
            wv0[k] = w4[(kb + k) * DD + dp];
            wv1[k] = w4[(kb + k) * DD + dp + 64];
        }
        #pragma unroll
        for (int r = 0; r < 8; ++r) {
            float a0 = 0.f, a1 = 0.f;
            #pragma unroll
            for (int q = 0; q < 4; ++q) {
                const float4 uv = *(const float4*)&u1s[r * 128 + kb + q * 4];
                a0 = fmaf(uv.x, wv0[q*4+0], a0); a1 = fmaf(uv.x, wv1[q*4+0], a1);
                a0 = fmaf(uv.y, wv0[q*4+1], a0); a1 = fmaf(uv.y, wv1[q*4+1], a1);
                a0 = fmaf(uv.z, wv0[q*4+2], a0); a1 = fmaf(uv.z, wv1[q*4+2], a1);
                a0 = fmaf(uv.w, wv0[q*4+3], a0); a1 = fmaf(uv.w, wv1[q*4+3], a1);
            }
            part[kg * 1024 + r * 128 + dp]      = a0;
            part[kg * 1024 + r * 128 + dp + 64] = a1;
        }
    }
    __syncthreads();
    #pragma unroll
    for (int m = 0; m < 2; ++m) {
        int idx = tid + m * 512;
        int r = idx >> 7, d = idx & 127;
        float s = part[idx];
        #pragma unroll
        for (int w = 1; w < 8; ++w) s += part[w * 1024 + idx];
        resS[idx] = xs[idx] + s + b4[d];
    }
    __syncthreads();

    // LayerNorm: one wave per row, 2 d's per lane
    {
        const int r = tid >> 6, l = tid & 63;
        const float2 v = *(const float2*)&resS[r * 128 + l * 2];
        float s1 = v.x + v.y;
        float s2 = v.x * v.x + v.y * v.y;
        #pragma unroll
        for (int m = 32; m; m >>= 1) {
            s1 += __shfl_xor(s1, m);
            s2 += __shfl_xor(s2, m);
        }
        const float mu = s1 * (1.f / DD);
        const float rs = rsqrtf(s2 * (1.f / DD) - mu * mu + LN_EPS);
        const int d = l * 2;
        const float2 gv = *(const float2*)&g[d];
        const float2 bv = *(const float2*)&bet[d];
        float2 o;
        o.x = (v.x - mu) * rs * gv.x + bv.x;
        o.y = (v.y - mu) * rs * gv.y + bv.y;
        *(float2*)&out[((size_t)b * NN + i0 + r) * DD + d] = o;
    }
}

extern "C" void kernel_launch(void* const* d_in, const int* in_sizes, int n_in,
                              void* d_out, int out_size, void* d_ws, size_t ws_size,
                              hipStream_t stream) {
    (void)in_sizes; (void)n_in; (void)out_size; (void)ws_size;
    const float* x      = (const float*)d_in[0];
    const float* adj    = (const float*)d_in[1];
    const float* msg_w1 = (const float*)d_in[2];
    const float* msg_b1 = (const float*)d_in[3];
    const float* msg_w2 = (const float*)d_in[4];
    const float* msg_b2 = (const float*)d_in[5];
    const float* upd_w1 = (const float*)d_in[6];
    const float* upd_b1 = (const float*)d_in[7];
    const float* upd_w2 = (const float*)d_in[8];
    const float* upd_b2 = (const float*)d_in[9];
    const float* ln_g   = (const float*)d_in[10];
    const float* ln_b   = (const float*)d_in[11];
    float* out = (float*)d_out;

    float* hjb = (float*)d_ws;   // B*N*D floats

    kf_all<<<dim3(256), dim3(512), 0, stream>>>(adj, x, msg_w1, msg_b1,
                                                msg_w2, msg_b2,
                                                upd_w1, upd_b1, upd_w2, upd_b2,
                                                ln_g, ln_b, hjb, out);
}

// Round 19
// 24.933 us; speedup vs baseline: 4.0441x; 4.0441x over previous
//
#include <hip/hip_runtime.h>

#define BB 8
#define NN 256
#define DD 128
#define LN_EPS 1e-5f

// ---------------------------------------------------------------------------
// k_proj: hi = x @ w1[:D],  hjb = x @ w1[D:] + b1
// grid 256 blocks (8 rows) x 1024 threads (16 waves/CU = 4/SIMD).
// dp = tid&127 (output col), kg = tid>>7 (8-way k-split, 16 k each).
// XCD-affinity: batch = bid & 7.
// ---------------------------------------------------------------------------
__global__ __launch_bounds__(1024, 4) void k_proj(const float* __restrict__ x,
                                                  const float* __restrict__ w1,
                                                  const float* __restrict__ b1,
                                                  float* __restrict__ hi,
                                                  float* __restrict__ hjb) {
    __shared__ float xs[8 * DD];       // 4 KB
    __shared__ float part[16384];      // 64 KB: A @0, B @8192
    const int bid  = blockIdx.x;
    const int row0 = (bid & 7) * NN + (bid >> 3) * 8;   // XCD-affine
    const int tid  = threadIdx.x;
    xs[tid] = x[row0 * DD + tid];      // 1024 = 8*128 exactly
    __syncthreads();

    const int dp = tid & 127;
    const int kg = tid >> 7;     // 0..7
    const int kb = kg * 16;

    float aA[8] = {}, aB[8] = {};
    #pragma unroll
    for (int k4 = 0; k4 < 4; ++k4) {
        const int k0 = kb + k4 * 4;
        float wa[4], wb[4];
        #pragma unroll
        for (int q = 0; q < 4; ++q) {
            wa[q] = w1[(k0 + q) * DD + dp];
            wb[q] = w1[(DD + k0 + q) * DD + dp];
        }
        #pragma unroll
        for (int r = 0; r < 8; ++r) {
            const float4 xv = *(const float4*)&xs[r * DD + k0];  // broadcast
            aA[r] = fmaf(xv.x, wa[0], aA[r]);
            aA[r] = fmaf(xv.y, wa[1], aA[r]);
            aA[r] = fmaf(xv.z, wa[2], aA[r]);
            aA[r] = fmaf(xv.w, wa[3], aA[r]);
            aB[r] = fmaf(xv.x, wb[0], aB[r]);
            aB[r] = fmaf(xv.y, wb[1], aB[r]);
            aB[r] = fmaf(xv.z, wb[2], aB[r]);
            aB[r] = fmaf(xv.w, wb[3], aB[r]);
        }
    }
    #pragma unroll
    for (int r = 0; r < 8; ++r) {
        part[kg * 1024 + r * DD + dp]        = aA[r];
        part[8192 + kg * 1024 + r * DD + dp] = aB[r];
    }
    __syncthreads();
    {
        int r = tid >> 7, d = tid & 127;
        float sa = 0.f, sb = 0.f;
        #pragma unroll
        for (int w = 0; w < 8; ++w) {
            sa += part[w * 1024 + r * DD + d];
            sb += part[8192 + w * 1024 + r * DD + d];
        }
        hi [(row0 + r) * DD + d] = sa;
        hjb[(row0 + r) * DD + d] = sb + b1[d];
    }
}

// ---------------------------------------------------------------------------
// k_fused: champion work decomposition (256 blocks, 8 rows, 64-j LDS tiles)
// at 1024 threads (16 waves/CU = 4/SIMD). XCD-affine (b = bid & 7).
// Pair: dq = tid&31 (4 d), row = (tid>>5)&7, jh = tid>>8 (4-way j-split,
// 16 j each); partials [4][8][128] alias dead hjs. Tail: 1 col/thread
// (dp = tid&127), kg = tid>>7 (8-way k-split); partT[8][8][128] alias.
// smem floats: [0,8192) hjs / partP(4K) / partT(8K)
//   [8192,10240) a_t[8][256]; aliases u1s@8192, resS@9216 after pair
//   [10240,11264) xs | [11264,12288) ssp | [12288,13312) aggs
//   [13312,13320) asum_s
// ---------------------------------------------------------------------------
__global__ __launch_bounds__(1024, 4) void k_fused(const float* __restrict__ adj,
                                                   const float* __restrict__ x,
                                                   const float* __restrict__ hi,
                                                   const float* __restrict__ hjb,
                                                   const float* __restrict__ w2,
                                                   const float* __restrict__ b2,
                                                   const float* __restrict__ w3,
                                                   const float* __restrict__ b3,
                                                   const float* __restrict__ w4,
                                                   const float* __restrict__ b4,
                                                   const float* __restrict__ g,
                                                   const float* __restrict__ bet,
                                                   float* __restrict__ out) {
    __shared__ float smem[13320];
    float* const hjs    = smem;           // [64][128]
    float* const partP  = smem;           // [4][8][128] alias
    float* const partT  = smem;           // [8][8][128] alias
    float* const a_t    = smem + 8192;    // [8][256]
    float* const u1s    = smem + 8192;    // [8][128] alias (a_t dead)
    float* const resS   = smem + 9216;    // [8][128] alias
    float* const xs     = smem + 10240;   // [8][128]
    float* const ssp    = smem + 11264;   // [8][128]
    float* const aggs   = smem + 12288;   // [8][128]
    float* const asum_s = smem + 13312;   // [8]

    const int bid = blockIdx.x;
    const int b   = bid & 7;              // XCD-affine batch
    const int i0  = (bid >> 3) * 8;
    const int tid = threadIdx.x;

    // ---- stage masked adjacency + x rows
    #pragma unroll
    for (int t = 0; t < 2; ++t) {
        int idx = tid + t * 1024;           // 0..2047
        int il = idx >> 8, j = idx & 255;
        int ig = i0 + il;
        float av = adj[((size_t)b * NN + ig) * NN + j];
        a_t[il * 256 + j] = (j == ig) ? 0.f : av;
    }
    xs[tid] = x[((size_t)b * NN + i0) * DD + tid];
    __syncthreads();

    // ---- asum: waves 0..7, one row each
    if (tid < 512) {
        int r = tid >> 6, l = tid & 63;
        float s = a_t[r * 256 + l] + a_t[r * 256 + l + 64]
                + a_t[r * 256 + l + 128] + a_t[r * 256 + l + 192];
        #pragma unroll
        for (int m = 32; m; m >>= 1) s += __shfl_xor(s, m);
        if (l == 0) asum_s[r] = s;
    }

    // ---- pair: 4 tiles of 64 j; 4-way j-split (jh), 16 j per thread-tile
    const int dq  = tid & 31;        // d-quad
    const int row = (tid >> 5) & 7;
    const int jh  = tid >> 8;        // 0..3
    const float4 hi4 = *(const float4*)&hi[((size_t)b * NN + i0 + row) * DD + dq * 4];
    float4 acc = {0.f, 0.f, 0.f, 0.f};

    for (int jt = 0; jt < 4; ++jt) {
        __syncthreads();   // prev tile reads done (tt=0: staging visible)
        const float4* src = (const float4*)(hjb + ((size_t)b * NN + jt * 64) * DD);
        float4* dst = (float4*)hjs;
        #pragma unroll
        for (int t = 0; t < 2; ++t) dst[tid + t * 1024] = src[tid + t * 1024];
        __syncthreads();
        const int jb = jh * 16;
        #pragma unroll 8
        for (int jj = 0; jj < 16; ++jj) {
            const int jl = jb + jj;
            const float4 hv = *(const float4*)&hjs[jl * 128 + dq * 4];
            const float a = a_t[row * 256 + jt * 64 + jl];
            acc.x = fmaf(fmaxf(hi4.x + hv.x, 0.f), a, acc.x);
            acc.y = fmaf(fmaxf(hi4.y + hv.y, 0.f), a, acc.y);
            acc.z = fmaf(fmaxf(hi4.z + hv.z, 0.f), a, acc.z);
            acc.w = fmaf(fmaxf(hi4.w + hv.w, 0.f), a, acc.w);
        }
    }
    __syncthreads();       // last hjs reads done before partP alias writes
    *(float4*)&partP[jh * 1024 + row * 128 + dq * 4] = acc;
    __syncthreads();
    {
        float s = partP[tid] + partP[1024 + tid] + partP[2048 + tid] + partP[3072 + tid];
        ssp[tid] = s;
    }
    __syncthreads();

    // ---- tail: 1 col/thread (dp), 8-way k-split (kg), 16 k each
    const int dp = tid & 127;
    const int kg = tid >> 7;            // 0..7
    const int kb = kg * 16;

    // stage A: agg = ssp @ w2 (+ b2*asum at combine)
    {
        float w0[16];
        #pragma unroll
        for (int k = 0; k < 16; ++k) w0[k] = w2[(kb + k) * DD + dp];
        #pragma unroll
        for (int r = 0; r < 8; ++r) {
            float a0 = 0.f;
            #pragma unroll
            for (int q = 0; q < 4; ++q) {
                const float4 sv = *(const float4*)&ssp[r * 128 + kb + q * 4];
                a0 = fmaf(sv.x, w0[q*4+0], a0);
                a0 = fmaf(sv.y, w0[q*4+1], a0);
                a0 = fmaf(sv.z, w0[q*4+2], a0);
                a0 = fmaf(sv.w, w0[q*4+3], a0);
            }
            partT[kg * 1024 + r * 128 + dp] = a0;
        }
    }
    __syncthreads();
    {
        int r = tid >> 7, d = tid & 127;
        float s = 0.f;
        #pragma unroll
        for (int w = 0; w < 8; ++w) s += partT[w * 1024 + tid];
        aggs[tid] = s + b2[d] * asum_s[r];
    }
    __syncthreads();

    // stage B: u1 = relu(x@w3a + agg@w3b + b3)
    {
        float wa0[16], wb0[16];
        #pragma unroll
        for (int k = 0; k < 16; ++k) {
            wa0[k] = w3[(kb + k) * DD + dp];
            wb0[k] = w3[(DD + kb + k) * DD + dp];
        }
        #pragma unroll
        for (int r = 0; r < 8; ++r) {
            float a0 = 0.f;
            #pragma unroll
            for (int q = 0; q < 4; ++q) {
                const float4 xv = *(const float4*)&xs[r * 128 + kb + q * 4];
                const float4 av = *(const float4*)&aggs[r * 128 + kb + q * 4];
                a0 = fmaf(xv.x, wa0[q*4+0], a0);
                a0 = fmaf(xv.y, wa0[q*4+1], a0);
                a0 = fmaf(xv.z, wa0[q*4+2], a0);
                a0 = fmaf(xv.w, wa0[q*4+3], a0);
                a0 = fmaf(av.x, wb0[q*4+0], a0);
                a0 = fmaf(av.y, wb0[q*4+1], a0);
                a0 = fmaf(av.z, wb0[q*4+2], a0);
                a0 = fmaf(av.w, wb0[q*4+3], a0);
            }
            partT[kg * 1024 + r * 128 + dp] = a0;
        }
    }
    __syncthreads();
    {
        int d = tid & 127;
        float s = 0.f;
        #pragma unroll
        for (int w = 0; w < 8; ++w) s += partT[w * 1024 + tid];
        u1s[tid] = fmaxf(s + b3[d], 0.f);
    }
    __syncthreads();

    // stage C: upd = u1 @ w4; res = x + upd + b4
    {
        float w0[16];
        #pragma unroll
        for (int k = 0; k < 16; ++k) w0[k] = w4[(kb + k) * DD + dp];
        #pragma unroll
        for (int r = 0; r < 8; ++r) {
            float a0 = 0.f;
            #pragma unroll
            for (int q = 0; q < 4; ++q) {
                const float4 uv = *(const float4*)&u1s[r * 128 + kb + q * 4];
                a0 = fmaf(uv.x, w0[q*4+0], a0);
                a0 = fmaf(uv.y, w0[q*4+1], a0);
                a0 = fmaf(uv.z, w0[q*4+2], a0);
                a0 = fmaf(uv.w, w0[q*4+3], a0);
            }
            partT[kg * 1024 + r * 128 + dp] = a0;
        }
    }
    __syncthreads();
    {
        int d = tid & 127;
        float s = xs[tid] + b4[d];
        #pragma unroll
        for (int w = 0; w < 8; ++w) s += partT[w * 1024 + tid];
        resS[tid] = s;
    }
    __syncthreads();

    // ---- LayerNorm: waves 0..7, one row each, 2 d's per lane
    if (tid < 512) {
        const int r = tid >> 6, l = tid & 63;
        const float2 v = *(const float2*)&resS[r * 128 + l * 2];
        float s1 = v.x + v.y;
        float s2 = v.x * v.x + v.y * v.y;
        #pragma unroll
        for (int m = 32; m; m >>= 1) {
            s1 += __shfl_xor(s1, m);
            s2 += __shfl_xor(s2, m);
        }
        const float mu = s1 * (1.f / DD);
        const float rs = rsqrtf(s2 * (1.f / DD) - mu * mu + LN_EPS);
        const int d = l * 2;
        const float2 gv = *(const float2*)&g[d];
        const float2 bv = *(const float2*)&bet[d];
        float2 o;
        o.x = (v.x - mu) * rs * gv.x + bv.x;
        o.y = (v.y - mu) * rs * gv.y + bv.y;
        *(float2*)&out[((size_t)b * NN + i0 + r) * DD + d] = o;
    }
}

extern "C" void kernel_launch(void* const* d_in, const int* in_sizes, int n_in,
                              void* d_out, int out_size, void* d_ws, size_t ws_size,
                              hipStream_t stream) {
    (void)in_sizes; (void)n_in; (void)out_size; (void)ws_size;
    const float* x      = (const float*)d_in[0];
    const float* adj    = (const float*)d_in[1];
    const float* msg_w1 = (const float*)d_in[2];
    const float* msg_b1 = (const float*)d_in[3];
    const float* msg_w2 = (const float*)d_in[4];
    const float* msg_b2 = (const float*)d_in[5];
    const float* upd_w1 = (const float*)d_in[6];
    const float* upd_b1 = (const float*)d_in[7];
    const float* upd_w2 = (const float*)d_in[8];
    const float* upd_b2 = (const float*)d_in[9];
    const float* ln_g   = (const float*)d_in[10];
    const float* ln_b   = (const float*)d_in[11];
    float* out = (float*)d_out;

    const size_t BND = (size_t)BB * NN * DD;
    float* ws  = (float*)d_ws;
    float* hi  = ws;            // B*N*D
    float* hjb = ws + BND;      // B*N*D

    k_proj<<<dim3(256), dim3(1024), 0, stream>>>(x, msg_w1, msg_b1, hi, hjb);
    k_fused<<<dim3(256), dim3(1024), 0, stream>>>(adj, x, hi, hjb,
                                                  msg_w2, msg_b2,
                                                  upd_w1, upd_b1, upd_w2, upd_b2,
                                                  ln_g, ln_b, out);
}